// Round 3
// baseline (608.164 us; speedup 1.0000x reference)
//
#include <hip/hip_runtime.h>

// Problem constants (fixed by the reference setup)
#define N_NODES 50000
#define IN_DIM 256
#define OUT_DIM 128
#define NNZ 800000          // nnz for feat, adj1, adj2 each
#define SCAN_N (3 * N_NODES)        // 150000 row counters (feat | adj1 | adj2)
#define TOTAL_NNZ (3 * NNZ)         // 2.4M sorted entries
#define SCAN_BLOCKS ((SCAN_N + 255) / 256)   // 586

// Packed CSR entry: low 32 bits = col, high 32 bits = value bits.
static __device__ __forceinline__ unsigned long long pack_cv(int c, float v) {
    return (unsigned long long)(unsigned)c |
           ((unsigned long long)__float_as_uint(v) << 32);
}

// -----------------------------------------------------------------------------
// CSR build: histogram -> exclusive scan -> scatter (counting sort by row).
// Unified segments: feat rows [0,50K), adj1 [50K,100K), adj2 [100K,150K).
// -----------------------------------------------------------------------------
__global__ void hist_kernel(const int* __restrict__ fr,
                            const int* __restrict__ a1r,
                            const int* __restrict__ a2r,
                            int* __restrict__ cnt) {
    int e = blockIdx.x * blockDim.x + threadIdx.x;
    if (e >= NNZ) return;
    atomicAdd(&cnt[fr[e]], 1);
    atomicAdd(&cnt[N_NODES + a1r[e]], 1);
    atomicAdd(&cnt[2 * N_NODES + a2r[e]], 1);
}

__global__ void scan_block_kernel(const int* __restrict__ cnt,
                                  int* __restrict__ starts,
                                  int* __restrict__ bsum) {
    __shared__ int tmp[256];
    int g = blockIdx.x * 256 + threadIdx.x;
    int v = (g < SCAN_N) ? cnt[g] : 0;
    tmp[threadIdx.x] = v;
    __syncthreads();
    for (int off = 1; off < 256; off <<= 1) {
        int t = (threadIdx.x >= off) ? tmp[threadIdx.x - off] : 0;
        __syncthreads();
        tmp[threadIdx.x] += t;
        __syncthreads();
    }
    int incl = tmp[threadIdx.x];
    if (g < SCAN_N) starts[g] = incl - v;          // exclusive
    if (threadIdx.x == 255) bsum[blockIdx.x] = incl;
}

__global__ void scan_bsum_kernel(int* __restrict__ bsum, int nb) {
    __shared__ int tmp[1024];
    int t = threadIdx.x;
    int v = (t < nb) ? bsum[t] : 0;
    tmp[t] = v;
    __syncthreads();
    for (int off = 1; off < 1024; off <<= 1) {
        int x = (t >= off) ? tmp[t - off] : 0;
        __syncthreads();
        tmp[t] += x;
        __syncthreads();
    }
    if (t < nb) bsum[t] = tmp[t] - v;              // exclusive block offsets
}

__global__ void scan_add_kernel(int* __restrict__ starts,
                                const int* __restrict__ bsum,
                                int* __restrict__ cursor) {
    int g = blockIdx.x * 256 + threadIdx.x;
    if (g < SCAN_N) {
        int s = starts[g] + bsum[blockIdx.x];
        starts[g] = s;
        cursor[g] = s;
    }
}

// Packed 8B nontemporal scatter: one store per entry instead of two, nt flag
// avoids RFO + full-line writeback for these random single-touch writes.
__global__ void scatter_kernel(const int* __restrict__ fr, const int* __restrict__ fc,
                               const float* __restrict__ fv,
                               const int* __restrict__ a1r, const int* __restrict__ a1c,
                               const float* __restrict__ a1v,
                               const int* __restrict__ a2r, const int* __restrict__ a2c,
                               const float* __restrict__ a2v,
                               int* __restrict__ cursor,
                               unsigned long long* __restrict__ spair) {
    int e = blockIdx.x * blockDim.x + threadIdx.x;
    if (e >= NNZ) return;
    int p;
    p = atomicAdd(&cursor[fr[e]], 1);
    __builtin_nontemporal_store(pack_cv(fc[e], fv[e]), &spair[p]);
    p = atomicAdd(&cursor[N_NODES + a1r[e]], 1);
    __builtin_nontemporal_store(pack_cv(a1c[e], a1v[e]), &spair[p]);
    p = atomicAdd(&cursor[2 * N_NODES + a2r[e]], 1);
    __builtin_nontemporal_store(pack_cv(a2c[e], a2v[e]), &spair[p]);
}

// -----------------------------------------------------------------------------
// Phase 1: per-row gather  xw{1,2}[r,:] = sum_e v_e * W{1,2}[c_e,:]
// 32 lanes per row, float4 per lane (128 cols). No atomics, single write.
// -----------------------------------------------------------------------------
__global__ void feat_gather_kernel(const int* __restrict__ starts,
                                   const unsigned long long* __restrict__ spair,
                                   const float4* __restrict__ W1,
                                   const float4* __restrict__ W2,
                                   float4* __restrict__ xw1,
                                   float4* __restrict__ xw2) {
    int lane = threadIdx.x & 31;
    int sub  = threadIdx.x >> 5;
    int r = blockIdx.x * 8 + sub;
    if (r >= N_NODES) return;
    int s = starts[r];
    int e = starts[r + 1];            // starts[50000] == 800000 (adj1 base)
    float4 a1 = make_float4(0.f, 0.f, 0.f, 0.f);
    float4 a2 = make_float4(0.f, 0.f, 0.f, 0.f);
    for (int i = s; i < e; i++) {
        unsigned long long pk = __builtin_nontemporal_load(&spair[i]);
        int   c = (int)(unsigned)(pk & 0xffffffffull);
        float v = __uint_as_float((unsigned)(pk >> 32));
        float4 w1 = W1[c * 32 + lane];
        float4 w2 = W2[c * 32 + lane];
        a1.x += v * w1.x; a1.y += v * w1.y; a1.z += v * w1.z; a1.w += v * w1.w;
        a2.x += v * w2.x; a2.y += v * w2.y; a2.z += v * w2.z; a2.w += v * w2.w;
    }
    xw1[r * 32 + lane] = a1;
    xw2[r * 32 + lane] = a2;
}

// -----------------------------------------------------------------------------
// Phase 2: out[r,:] = relu( sum_adj1 v*xw1[c,:] + sum_adj2 v*xw2[c,:] )
// -----------------------------------------------------------------------------
__global__ void adj_gather_kernel(const int* __restrict__ starts,
                                  const unsigned long long* __restrict__ spair,
                                  const float4* __restrict__ xw1,
                                  const float4* __restrict__ xw2,
                                  float4* __restrict__ out) {
    int lane = threadIdx.x & 31;
    int sub  = threadIdx.x >> 5;
    int r = blockIdx.x * 8 + sub;
    if (r >= N_NODES) return;
    int s1 = starts[N_NODES + r];
    int e1 = starts[N_NODES + r + 1];        // starts[100000] == adj2 base
    int s2 = starts[2 * N_NODES + r];
    int e2 = (r == N_NODES - 1) ? TOTAL_NNZ : starts[2 * N_NODES + r + 1];
    float4 acc = make_float4(0.f, 0.f, 0.f, 0.f);
    for (int i = s1; i < e1; i++) {
        unsigned long long pk = __builtin_nontemporal_load(&spair[i]);
        int   c = (int)(unsigned)(pk & 0xffffffffull);
        float v = __uint_as_float((unsigned)(pk >> 32));
        float4 x = xw1[c * 32 + lane];
        acc.x += v * x.x; acc.y += v * x.y; acc.z += v * x.z; acc.w += v * x.w;
    }
    for (int i = s2; i < e2; i++) {
        unsigned long long pk = __builtin_nontemporal_load(&spair[i]);
        int   c = (int)(unsigned)(pk & 0xffffffffull);
        float v = __uint_as_float((unsigned)(pk >> 32));
        float4 x = xw2[c * 32 + lane];
        acc.x += v * x.x; acc.y += v * x.y; acc.z += v * x.z; acc.w += v * x.w;
    }
    acc.x = fmaxf(acc.x, 0.f); acc.y = fmaxf(acc.y, 0.f);
    acc.z = fmaxf(acc.z, 0.f); acc.w = fmaxf(acc.w, 0.f);
    out[r * 32 + lane] = acc;
}

extern "C" void kernel_launch(void* const* d_in, const int* in_sizes, int n_in,
                              void* d_out, int out_size, void* d_ws, size_t ws_size,
                              hipStream_t stream) {
    const int*   feat_row  = (const int*)  d_in[0];
    const int*   feat_col  = (const int*)  d_in[1];
    const float* feat_vals = (const float*)d_in[2];
    const int*   adj1_row  = (const int*)  d_in[3];
    const int*   adj1_col  = (const int*)  d_in[4];
    const float* adj1_vals = (const float*)d_in[5];
    const int*   adj2_row  = (const int*)  d_in[6];
    const int*   adj2_col  = (const int*)  d_in[7];
    const float* adj2_vals = (const float*)d_in[8];
    const float* W1        = (const float*)d_in[9];
    const float* W2        = (const float*)d_in[10];

    // Workspace layout (all 16B-aligned offsets)
    char* ws = (char*)d_ws;
    float* xw1 = (float*)ws;                    ws += (size_t)N_NODES * OUT_DIM * 4;  // 25.6 MB
    float* xw2 = (float*)ws;                    ws += (size_t)N_NODES * OUT_DIM * 4;  // 25.6 MB
    unsigned long long* spair = (unsigned long long*)ws;
                                                ws += (size_t)TOTAL_NNZ * 8;          // 19.2 MB
    int* cnt    = (int*)ws;                     ws += (size_t)SCAN_N * 4;             // 600 KB
    int* starts = (int*)ws;                     ws += (size_t)SCAN_N * 4;             // 600 KB
    int* cursor = (int*)ws;                     ws += (size_t)SCAN_N * 4;             // 600 KB
    int* bsum   = (int*)ws;                     ws += 1024 * 4;

    // Zero only the histogram counters (everything else is fully overwritten).
    hipMemsetAsync(cnt, 0, SCAN_N * sizeof(int), stream);

    const int block = 256;
    const int grid_e = (NNZ + block - 1) / block;                // 3125

    hist_kernel<<<grid_e, block, 0, stream>>>(feat_row, adj1_row, adj2_row, cnt);
    scan_block_kernel<<<SCAN_BLOCKS, 256, 0, stream>>>(cnt, starts, bsum);
    scan_bsum_kernel<<<1, 1024, 0, stream>>>(bsum, SCAN_BLOCKS);
    scan_add_kernel<<<SCAN_BLOCKS, 256, 0, stream>>>(starts, bsum, cursor);
    scatter_kernel<<<grid_e, block, 0, stream>>>(
        feat_row, feat_col, feat_vals,
        adj1_row, adj1_col, adj1_vals,
        adj2_row, adj2_col, adj2_vals,
        cursor, spair);

    const int grid_rows = (N_NODES + 7) / 8;                     // 6250 blocks, 8 rows each
    feat_gather_kernel<<<grid_rows, 256, 0, stream>>>(
        starts, spair, (const float4*)W1, (const float4*)W2,
        (float4*)xw1, (float4*)xw2);
    adj_gather_kernel<<<grid_rows, 256, 0, stream>>>(
        starts, spair, (const float4*)xw1, (const float4*)xw2,
        (float4*)d_out);
}

// Round 4
// 593.852 us; speedup vs baseline: 1.0241x; 1.0241x over previous
//
#include <hip/hip_runtime.h>

// Problem constants (fixed by the reference setup)
#define N_NODES 50000
#define IN_DIM 256
#define OUT_DIM 128
#define NNZ 800000          // nnz for feat, adj1, adj2 each
#define SCAN_N (3 * N_NODES)        // 150000 row counters (feat | adj1 | adj2)
#define TOTAL_NNZ (3 * NNZ)         // 2.4M sorted entries
#define SCAN_BLOCKS ((SCAN_N + 255) / 256)   // 586

// Packed CSR entry: low 32 bits = col, high 32 bits = value bits.
static __device__ __forceinline__ unsigned long long pack_cv(int c, float v) {
    return (unsigned long long)(unsigned)c |
           ((unsigned long long)__float_as_uint(v) << 32);
}

// -----------------------------------------------------------------------------
// CSR build: histogram -> exclusive scan -> scatter (counting sort by row).
// Unified segments: feat rows [0,50K), adj1 [50K,100K), adj2 [100K,150K).
// -----------------------------------------------------------------------------
__global__ void hist_kernel(const int* __restrict__ fr,
                            const int* __restrict__ a1r,
                            const int* __restrict__ a2r,
                            int* __restrict__ cnt) {
    int e = blockIdx.x * blockDim.x + threadIdx.x;
    if (e >= NNZ) return;
    atomicAdd(&cnt[fr[e]], 1);
    atomicAdd(&cnt[N_NODES + a1r[e]], 1);
    atomicAdd(&cnt[2 * N_NODES + a2r[e]], 1);
}

__global__ void scan_block_kernel(const int* __restrict__ cnt,
                                  int* __restrict__ starts,
                                  int* __restrict__ bsum) {
    __shared__ int tmp[256];
    int g = blockIdx.x * 256 + threadIdx.x;
    int v = (g < SCAN_N) ? cnt[g] : 0;
    tmp[threadIdx.x] = v;
    __syncthreads();
    for (int off = 1; off < 256; off <<= 1) {
        int t = (threadIdx.x >= off) ? tmp[threadIdx.x - off] : 0;
        __syncthreads();
        tmp[threadIdx.x] += t;
        __syncthreads();
    }
    int incl = tmp[threadIdx.x];
    if (g < SCAN_N) starts[g] = incl - v;          // exclusive
    if (threadIdx.x == 255) bsum[blockIdx.x] = incl;
}

__global__ void scan_bsum_kernel(int* __restrict__ bsum, int nb) {
    __shared__ int tmp[1024];
    int t = threadIdx.x;
    int v = (t < nb) ? bsum[t] : 0;
    tmp[t] = v;
    __syncthreads();
    for (int off = 1; off < 1024; off <<= 1) {
        int x = (t >= off) ? tmp[t - off] : 0;
        __syncthreads();
        tmp[t] += x;
        __syncthreads();
    }
    if (t < nb) bsum[t] = tmp[t] - v;              // exclusive block offsets
}

__global__ void scan_add_kernel(int* __restrict__ starts,
                                const int* __restrict__ bsum,
                                int* __restrict__ cursor) {
    int g = blockIdx.x * 256 + threadIdx.x;
    if (g < SCAN_N) {
        int s = starts[g] + bsum[blockIdx.x];
        starts[g] = s;
        cursor[g] = s;
    }
}

// Packed 8B scatter with REGULAR (cached) stores: L2 absorbs and merges the
// ~16 adjacent records per row segment. (nt stores regressed: R3 608 vs R2 487.)
__global__ void scatter_kernel(const int* __restrict__ fr, const int* __restrict__ fc,
                               const float* __restrict__ fv,
                               const int* __restrict__ a1r, const int* __restrict__ a1c,
                               const float* __restrict__ a1v,
                               const int* __restrict__ a2r, const int* __restrict__ a2c,
                               const float* __restrict__ a2v,
                               int* __restrict__ cursor,
                               unsigned long long* __restrict__ spair) {
    int e = blockIdx.x * blockDim.x + threadIdx.x;
    if (e >= NNZ) return;
    int p;
    p = atomicAdd(&cursor[fr[e]], 1);
    spair[p] = pack_cv(fc[e], fv[e]);
    p = atomicAdd(&cursor[N_NODES + a1r[e]], 1);
    spair[p] = pack_cv(a1c[e], a1v[e]);
    p = atomicAdd(&cursor[2 * N_NODES + a2r[e]], 1);
    spair[p] = pack_cv(a2c[e], a2v[e]);
}

// -----------------------------------------------------------------------------
// Phase 1: per-row gather  xw{1,2}[r,:] = sum_e v_e * W{1,2}[c_e,:]
// 32 lanes per row, float4 per lane (128 cols). No atomics, single write.
// -----------------------------------------------------------------------------
__global__ void feat_gather_kernel(const int* __restrict__ starts,
                                   const unsigned long long* __restrict__ spair,
                                   const float4* __restrict__ W1,
                                   const float4* __restrict__ W2,
                                   float4* __restrict__ xw1,
                                   float4* __restrict__ xw2) {
    int lane = threadIdx.x & 31;
    int sub  = threadIdx.x >> 5;
    int r = blockIdx.x * 8 + sub;
    if (r >= N_NODES) return;
    int s = starts[r];
    int e = starts[r + 1];            // starts[50000] == 800000 (adj1 base)
    float4 a1 = make_float4(0.f, 0.f, 0.f, 0.f);
    float4 a2 = make_float4(0.f, 0.f, 0.f, 0.f);
    for (int i = s; i < e; i++) {
        unsigned long long pk = __builtin_nontemporal_load(&spair[i]);
        int   c = (int)(unsigned)(pk & 0xffffffffull);
        float v = __uint_as_float((unsigned)(pk >> 32));
        float4 w1 = W1[c * 32 + lane];
        float4 w2 = W2[c * 32 + lane];
        a1.x += v * w1.x; a1.y += v * w1.y; a1.z += v * w1.z; a1.w += v * w1.w;
        a2.x += v * w2.x; a2.y += v * w2.y; a2.z += v * w2.z; a2.w += v * w2.w;
    }
    xw1[r * 32 + lane] = a1;
    xw2[r * 32 + lane] = a2;
}

// -----------------------------------------------------------------------------
// Phase 2: out[r,:] = relu( sum_adj1 v*xw1[c,:] + sum_adj2 v*xw2[c,:] )
// -----------------------------------------------------------------------------
__global__ void adj_gather_kernel(const int* __restrict__ starts,
                                  const unsigned long long* __restrict__ spair,
                                  const float4* __restrict__ xw1,
                                  const float4* __restrict__ xw2,
                                  float4* __restrict__ out) {
    int lane = threadIdx.x & 31;
    int sub  = threadIdx.x >> 5;
    int r = blockIdx.x * 8 + sub;
    if (r >= N_NODES) return;
    int s1 = starts[N_NODES + r];
    int e1 = starts[N_NODES + r + 1];        // starts[100000] == adj2 base
    int s2 = starts[2 * N_NODES + r];
    int e2 = (r == N_NODES - 1) ? TOTAL_NNZ : starts[2 * N_NODES + r + 1];
    float4 acc = make_float4(0.f, 0.f, 0.f, 0.f);
    for (int i = s1; i < e1; i++) {
        unsigned long long pk = __builtin_nontemporal_load(&spair[i]);
        int   c = (int)(unsigned)(pk & 0xffffffffull);
        float v = __uint_as_float((unsigned)(pk >> 32));
        float4 x = xw1[c * 32 + lane];
        acc.x += v * x.x; acc.y += v * x.y; acc.z += v * x.z; acc.w += v * x.w;
    }
    for (int i = s2; i < e2; i++) {
        unsigned long long pk = __builtin_nontemporal_load(&spair[i]);
        int   c = (int)(unsigned)(pk & 0xffffffffull);
        float v = __uint_as_float((unsigned)(pk >> 32));
        float4 x = xw2[c * 32 + lane];
        acc.x += v * x.x; acc.y += v * x.y; acc.z += v * x.z; acc.w += v * x.w;
    }
    acc.x = fmaxf(acc.x, 0.f); acc.y = fmaxf(acc.y, 0.f);
    acc.z = fmaxf(acc.z, 0.f); acc.w = fmaxf(acc.w, 0.f);
    out[r * 32 + lane] = acc;
}

extern "C" void kernel_launch(void* const* d_in, const int* in_sizes, int n_in,
                              void* d_out, int out_size, void* d_ws, size_t ws_size,
                              hipStream_t stream) {
    const int*   feat_row  = (const int*)  d_in[0];
    const int*   feat_col  = (const int*)  d_in[1];
    const float* feat_vals = (const float*)d_in[2];
    const int*   adj1_row  = (const int*)  d_in[3];
    const int*   adj1_col  = (const int*)  d_in[4];
    const float* adj1_vals = (const float*)d_in[5];
    const int*   adj2_row  = (const int*)  d_in[6];
    const int*   adj2_col  = (const int*)  d_in[7];
    const float* adj2_vals = (const float*)d_in[8];
    const float* W1        = (const float*)d_in[9];
    const float* W2        = (const float*)d_in[10];

    // Workspace layout (all 16B-aligned offsets)
    char* ws = (char*)d_ws;
    float* xw1 = (float*)ws;                    ws += (size_t)N_NODES * OUT_DIM * 4;  // 25.6 MB
    float* xw2 = (float*)ws;                    ws += (size_t)N_NODES * OUT_DIM * 4;  // 25.6 MB
    unsigned long long* spair = (unsigned long long*)ws;
                                                ws += (size_t)TOTAL_NNZ * 8;          // 19.2 MB
    int* cnt    = (int*)ws;                     ws += (size_t)SCAN_N * 4;             // 600 KB
    int* starts = (int*)ws;                     ws += (size_t)SCAN_N * 4;             // 600 KB
    int* cursor = (int*)ws;                     ws += (size_t)SCAN_N * 4;             // 600 KB
    int* bsum   = (int*)ws;                     ws += 1024 * 4;

    // Zero only the histogram counters (everything else is fully overwritten).
    hipMemsetAsync(cnt, 0, SCAN_N * sizeof(int), stream);

    const int block = 256;
    const int grid_e = (NNZ + block - 1) / block;                // 3125

    hist_kernel<<<grid_e, block, 0, stream>>>(feat_row, adj1_row, adj2_row, cnt);
    scan_block_kernel<<<SCAN_BLOCKS, 256, 0, stream>>>(cnt, starts, bsum);
    scan_bsum_kernel<<<1, 1024, 0, stream>>>(bsum, SCAN_BLOCKS);
    scan_add_kernel<<<SCAN_BLOCKS, 256, 0, stream>>>(starts, bsum, cursor);
    scatter_kernel<<<grid_e, block, 0, stream>>>(
        feat_row, feat_col, feat_vals,
        adj1_row, adj1_col, adj1_vals,
        adj2_row, adj2_col, adj2_vals,
        cursor, spair);

    const int grid_rows = (N_NODES + 7) / 8;                     // 6250 blocks, 8 rows each
    feat_gather_kernel<<<grid_rows, 256, 0, stream>>>(
        starts, spair, (const float4*)W1, (const float4*)W2,
        (float4*)xw1, (float4*)xw2);
    adj_gather_kernel<<<grid_rows, 256, 0, stream>>>(
        starts, spair, (const float4*)xw1, (const float4*)xw2,
        (float4*)d_out);
}

// Round 5
// 509.483 us; speedup vs baseline: 1.1937x; 1.1656x over previous
//
#include <hip/hip_runtime.h>

// Problem constants (fixed by the reference setup)
#define N_NODES 50000
#define IN_DIM 256
#define OUT_DIM 128
#define NNZ 800000          // nnz for feat, adj1, adj2 each
#define SCAN_N (3 * N_NODES)        // 150000 row counters (feat | adj1 | adj2)
#define TOTAL_NNZ (3 * NNZ)         // 2.4M sorted entries
#define SCAN_BLOCKS ((SCAN_N + 255) / 256)   // 586

// bf16 helpers (RNE pack)
static __device__ __forceinline__ unsigned short f2bf(float x) {
    unsigned u = __float_as_uint(x);
    u += 0x7fffu + ((u >> 16) & 1u);
    return (unsigned short)(u >> 16);
}
static __device__ __forceinline__ float bf2f(unsigned short b) {
    return __uint_as_float(((unsigned)b) << 16);
}

// -----------------------------------------------------------------------------
// CSR build: histogram -> exclusive scan -> scatter (counting sort by row).
// Unified segments: feat rows [0,50K), adj1 [50K,100K), adj2 [100K,150K).
// -----------------------------------------------------------------------------
// int4-vectorized histogram: 4 entries/thread, 12 atomics.
__global__ void hist_kernel(const int4* __restrict__ fr4,
                            const int4* __restrict__ a1r4,
                            const int4* __restrict__ a2r4,
                            int* __restrict__ cnt) {
    int t = blockIdx.x * blockDim.x + threadIdx.x;
    if (t >= NNZ / 4) return;
    int4 a = fr4[t];
    atomicAdd(&cnt[a.x], 1); atomicAdd(&cnt[a.y], 1);
    atomicAdd(&cnt[a.z], 1); atomicAdd(&cnt[a.w], 1);
    int4 b = a1r4[t];
    atomicAdd(&cnt[N_NODES + b.x], 1); atomicAdd(&cnt[N_NODES + b.y], 1);
    atomicAdd(&cnt[N_NODES + b.z], 1); atomicAdd(&cnt[N_NODES + b.w], 1);
    int4 c = a2r4[t];
    atomicAdd(&cnt[2 * N_NODES + c.x], 1); atomicAdd(&cnt[2 * N_NODES + c.y], 1);
    atomicAdd(&cnt[2 * N_NODES + c.z], 1); atomicAdd(&cnt[2 * N_NODES + c.w], 1);
}

__global__ void scan_block_kernel(const int* __restrict__ cnt,
                                  int* __restrict__ starts,
                                  int* __restrict__ bsum) {
    __shared__ int tmp[256];
    int g = blockIdx.x * 256 + threadIdx.x;
    int v = (g < SCAN_N) ? cnt[g] : 0;
    tmp[threadIdx.x] = v;
    __syncthreads();
    for (int off = 1; off < 256; off <<= 1) {
        int t = (threadIdx.x >= off) ? tmp[threadIdx.x - off] : 0;
        __syncthreads();
        tmp[threadIdx.x] += t;
        __syncthreads();
    }
    int incl = tmp[threadIdx.x];
    if (g < SCAN_N) starts[g] = incl - v;          // exclusive
    if (threadIdx.x == 255) bsum[blockIdx.x] = incl;
}

__global__ void scan_bsum_kernel(int* __restrict__ bsum, int nb) {
    __shared__ int tmp[1024];
    int t = threadIdx.x;
    int v = (t < nb) ? bsum[t] : 0;
    tmp[t] = v;
    __syncthreads();
    for (int off = 1; off < 1024; off <<= 1) {
        int x = (t >= off) ? tmp[t - off] : 0;
        __syncthreads();
        tmp[t] += x;
        __syncthreads();
    }
    if (t < nb) bsum[t] = tmp[t] - v;              // exclusive block offsets
}

__global__ void scan_add_kernel(int* __restrict__ starts,
                                const int* __restrict__ bsum,
                                int* __restrict__ cursor) {
    int g = blockIdx.x * 256 + threadIdx.x;
    if (g < SCAN_N) {
        int s = starts[g] + bsum[blockIdx.x];
        starts[g] = s;
        cursor[g] = s;
    }
}

// R2-structure scatter (two 4B arrays, cached stores — fastest measured) with
// 2 entries/thread for ILP: 6 independent atomic->store chains per thread.
__global__ void scatter_kernel(const int2* __restrict__ fr2, const int2* __restrict__ fc2,
                               const float2* __restrict__ fv2,
                               const int2* __restrict__ a1r2, const int2* __restrict__ a1c2,
                               const float2* __restrict__ a1v2,
                               const int2* __restrict__ a2r2, const int2* __restrict__ a2c2,
                               const float2* __restrict__ a2v2,
                               int* __restrict__ cursor,
                               int* __restrict__ scol, float* __restrict__ sval) {
    int t = blockIdx.x * blockDim.x + threadIdx.x;
    if (t >= NNZ / 2) return;
    int2 fr = fr2[t];   int2 fc = fc2[t];   float2 fv = fv2[t];
    int2 r1 = a1r2[t];  int2 c1 = a1c2[t];  float2 v1 = a1v2[t];
    int2 r2 = a2r2[t];  int2 c2 = a2c2[t];  float2 v2 = a2v2[t];
    int p;
    p = atomicAdd(&cursor[fr.x], 1);               scol[p] = fc.x; sval[p] = fv.x;
    p = atomicAdd(&cursor[fr.y], 1);               scol[p] = fc.y; sval[p] = fv.y;
    p = atomicAdd(&cursor[N_NODES + r1.x], 1);     scol[p] = c1.x; sval[p] = v1.x;
    p = atomicAdd(&cursor[N_NODES + r1.y], 1);     scol[p] = c1.y; sval[p] = v1.y;
    p = atomicAdd(&cursor[2 * N_NODES + r2.x], 1); scol[p] = c2.x; sval[p] = v2.x;
    p = atomicAdd(&cursor[2 * N_NODES + r2.y], 1); scol[p] = c2.y; sval[p] = v2.y;
}

// -----------------------------------------------------------------------------
// Phase 1: per-row gather  xw{1,2}[r,:] = sum_e v_e * W{1,2}[c_e,:]
// 32 lanes per row, float4 W loads; OUTPUT IS bf16 (halves phase-2 footprint:
// 25.6 MB combined -> fits aggregate L2).
// -----------------------------------------------------------------------------
__global__ void feat_gather_kernel(const int* __restrict__ starts,
                                   const int* __restrict__ scol,
                                   const float* __restrict__ sval,
                                   const float4* __restrict__ W1,
                                   const float4* __restrict__ W2,
                                   ushort4* __restrict__ xw1b,
                                   ushort4* __restrict__ xw2b) {
    int lane = threadIdx.x & 31;
    int sub  = threadIdx.x >> 5;
    int r = blockIdx.x * 8 + sub;
    if (r >= N_NODES) return;
    int s = starts[r];
    int e = starts[r + 1];            // starts[50000] == 800000 (adj1 base)
    float4 a1 = make_float4(0.f, 0.f, 0.f, 0.f);
    float4 a2 = make_float4(0.f, 0.f, 0.f, 0.f);
    for (int i = s; i < e; i++) {
        int c = scol[i];
        float v = sval[i];
        float4 w1 = W1[c * 32 + lane];
        float4 w2 = W2[c * 32 + lane];
        a1.x += v * w1.x; a1.y += v * w1.y; a1.z += v * w1.z; a1.w += v * w1.w;
        a2.x += v * w2.x; a2.y += v * w2.y; a2.z += v * w2.z; a2.w += v * w2.w;
    }
    ushort4 p1, p2;
    p1.x = f2bf(a1.x); p1.y = f2bf(a1.y); p1.z = f2bf(a1.z); p1.w = f2bf(a1.w);
    p2.x = f2bf(a2.x); p2.y = f2bf(a2.y); p2.z = f2bf(a2.z); p2.w = f2bf(a2.w);
    xw1b[r * 32 + lane] = p1;
    xw2b[r * 32 + lane] = p2;
}

// -----------------------------------------------------------------------------
// Phase 2: out[r,:] = relu( sum_adj1 v*xw1[c,:] + sum_adj2 v*xw2[c,:] )
// xw gathers are bf16 (8B/lane); accumulate fp32; out fp32.
// -----------------------------------------------------------------------------
__global__ void adj_gather_kernel(const int* __restrict__ starts,
                                  const int* __restrict__ scol,
                                  const float* __restrict__ sval,
                                  const ushort4* __restrict__ xw1b,
                                  const ushort4* __restrict__ xw2b,
                                  float4* __restrict__ out) {
    int lane = threadIdx.x & 31;
    int sub  = threadIdx.x >> 5;
    int r = blockIdx.x * 8 + sub;
    if (r >= N_NODES) return;
    int s1 = starts[N_NODES + r];
    int e1 = starts[N_NODES + r + 1];        // starts[100000] == adj2 base
    int s2 = starts[2 * N_NODES + r];
    int e2 = (r == N_NODES - 1) ? TOTAL_NNZ : starts[2 * N_NODES + r + 1];
    float4 acc = make_float4(0.f, 0.f, 0.f, 0.f);
    for (int i = s1; i < e1; i++) {
        int c = scol[i];
        float v = sval[i];
        ushort4 q = xw1b[c * 32 + lane];
        acc.x += v * bf2f(q.x); acc.y += v * bf2f(q.y);
        acc.z += v * bf2f(q.z); acc.w += v * bf2f(q.w);
    }
    for (int i = s2; i < e2; i++) {
        int c = scol[i];
        float v = sval[i];
        ushort4 q = xw2b[c * 32 + lane];
        acc.x += v * bf2f(q.x); acc.y += v * bf2f(q.y);
        acc.z += v * bf2f(q.z); acc.w += v * bf2f(q.w);
    }
    acc.x = fmaxf(acc.x, 0.f); acc.y = fmaxf(acc.y, 0.f);
    acc.z = fmaxf(acc.z, 0.f); acc.w = fmaxf(acc.w, 0.f);
    out[r * 32 + lane] = acc;
}

extern "C" void kernel_launch(void* const* d_in, const int* in_sizes, int n_in,
                              void* d_out, int out_size, void* d_ws, size_t ws_size,
                              hipStream_t stream) {
    const int*   feat_row  = (const int*)  d_in[0];
    const int*   feat_col  = (const int*)  d_in[1];
    const float* feat_vals = (const float*)d_in[2];
    const int*   adj1_row  = (const int*)  d_in[3];
    const int*   adj1_col  = (const int*)  d_in[4];
    const float* adj1_vals = (const float*)d_in[5];
    const int*   adj2_row  = (const int*)  d_in[6];
    const int*   adj2_col  = (const int*)  d_in[7];
    const float* adj2_vals = (const float*)d_in[8];
    const float* W1        = (const float*)d_in[9];
    const float* W2        = (const float*)d_in[10];

    // Workspace layout (all 16B-aligned offsets)
    char* ws = (char*)d_ws;
    ushort4* xw1b = (ushort4*)ws;               ws += (size_t)N_NODES * OUT_DIM * 2;  // 12.8 MB
    ushort4* xw2b = (ushort4*)ws;               ws += (size_t)N_NODES * OUT_DIM * 2;  // 12.8 MB
    int*   scol   = (int*)ws;                   ws += (size_t)TOTAL_NNZ * 4;          // 9.6 MB
    float* sval   = (float*)ws;                 ws += (size_t)TOTAL_NNZ * 4;          // 9.6 MB
    int*   cnt    = (int*)ws;                   ws += (size_t)SCAN_N * 4;             // 600 KB
    int*   starts = (int*)ws;                   ws += (size_t)SCAN_N * 4;             // 600 KB
    int*   cursor = (int*)ws;                   ws += (size_t)SCAN_N * 4;             // 600 KB
    int*   bsum   = (int*)ws;                   ws += 1024 * 4;

    // Zero only the histogram counters (everything else is fully overwritten).
    hipMemsetAsync(cnt, 0, SCAN_N * sizeof(int), stream);

    const int block = 256;

    const int grid_h = (NNZ / 4 + block - 1) / block;            // 782
    hist_kernel<<<grid_h, block, 0, stream>>>(
        (const int4*)feat_row, (const int4*)adj1_row, (const int4*)adj2_row, cnt);

    scan_block_kernel<<<SCAN_BLOCKS, 256, 0, stream>>>(cnt, starts, bsum);
    scan_bsum_kernel<<<1, 1024, 0, stream>>>(bsum, SCAN_BLOCKS);
    scan_add_kernel<<<SCAN_BLOCKS, 256, 0, stream>>>(starts, bsum, cursor);

    const int grid_s = (NNZ / 2 + block - 1) / block;            // 1563
    scatter_kernel<<<grid_s, block, 0, stream>>>(
        (const int2*)feat_row, (const int2*)feat_col, (const float2*)feat_vals,
        (const int2*)adj1_row, (const int2*)adj1_col, (const float2*)adj1_vals,
        (const int2*)adj2_row, (const int2*)adj2_col, (const float2*)adj2_vals,
        cursor, scol, sval);

    const int grid_rows = N_NODES / 8;                           // 6250 blocks, 8 rows each
    feat_gather_kernel<<<grid_rows, 256, 0, stream>>>(
        starts, scol, sval, (const float4*)W1, (const float4*)W2, xw1b, xw2b);
    adj_gather_kernel<<<grid_rows, 256, 0, stream>>>(
        starts, scol, sval, xw1b, xw2b, (float4*)d_out);
}

// Round 7
// 408.434 us; speedup vs baseline: 1.4890x; 1.2474x over previous
//
#include <hip/hip_runtime.h>
#include <hip/hip_fp16.h>

// Problem constants (fixed by the reference setup)
#define N_NODES 50000
#define IN_DIM 256
#define OUT_DIM 128
#define NNZ 800000          // nnz for feat, adj1, adj2 each
#define SCAN_N (3 * N_NODES)        // 150000 row counters (feat | adj1 | adj2)
#define TOTAL_NNZ (3 * NNZ)         // 2.4M sorted entries
#define SCAN_BLOCKS ((SCAN_N + 255) / 256)   // 586

// Native clang vector types — __builtin_nontemporal_* requires these
// (HIP_vector_type structs are rejected).
typedef int   vi4 __attribute__((ext_vector_type(4)));
typedef float vf4 __attribute__((ext_vector_type(4)));

// Packed entry: [col:16 | fp16(val):16].  adj cols < 50000 < 65536, feat cols < 256.
static __device__ __forceinline__ unsigned pack_cv(int c, float v) {
    return ((unsigned)c << 16) | (unsigned)__half_as_ushort(__float2half(v));
}
static __device__ __forceinline__ int   upk_c(unsigned pk) { return (int)(pk >> 16); }
static __device__ __forceinline__ float upk_v(unsigned pk) {
    return __half2float(__ushort_as_half((unsigned short)(pk & 0xffffu)));
}
static __device__ __forceinline__ float h2f(unsigned short h) {
    return __half2float(__ushort_as_half(h));
}

// -----------------------------------------------------------------------------
// CSR build: histogram -> exclusive scan -> scatter (counting sort by row).
// Unified segments: feat rows [0,50K), adj1 [50K,100K), adj2 [100K,150K).
// -----------------------------------------------------------------------------
__global__ void hist_kernel(const vi4* __restrict__ fr4,
                            const vi4* __restrict__ a1r4,
                            const vi4* __restrict__ a2r4,
                            int* __restrict__ cnt) {
    int t = blockIdx.x * blockDim.x + threadIdx.x;
    if (t >= NNZ / 4) return;
    vi4 a = __builtin_nontemporal_load(&fr4[t]);
    atomicAdd(&cnt[a.x], 1); atomicAdd(&cnt[a.y], 1);
    atomicAdd(&cnt[a.z], 1); atomicAdd(&cnt[a.w], 1);
    vi4 b = __builtin_nontemporal_load(&a1r4[t]);
    atomicAdd(&cnt[N_NODES + b.x], 1); atomicAdd(&cnt[N_NODES + b.y], 1);
    atomicAdd(&cnt[N_NODES + b.z], 1); atomicAdd(&cnt[N_NODES + b.w], 1);
    vi4 c = __builtin_nontemporal_load(&a2r4[t]);
    atomicAdd(&cnt[2 * N_NODES + c.x], 1); atomicAdd(&cnt[2 * N_NODES + c.y], 1);
    atomicAdd(&cnt[2 * N_NODES + c.z], 1); atomicAdd(&cnt[2 * N_NODES + c.w], 1);
}

__global__ void scan_block_kernel(const int* __restrict__ cnt,
                                  int* __restrict__ starts,
                                  int* __restrict__ bsum) {
    __shared__ int tmp[256];
    int g = blockIdx.x * 256 + threadIdx.x;
    int v = (g < SCAN_N) ? cnt[g] : 0;
    tmp[threadIdx.x] = v;
    __syncthreads();
    for (int off = 1; off < 256; off <<= 1) {
        int t = (threadIdx.x >= off) ? tmp[threadIdx.x - off] : 0;
        __syncthreads();
        tmp[threadIdx.x] += t;
        __syncthreads();
    }
    int incl = tmp[threadIdx.x];
    if (g < SCAN_N) starts[g] = incl - v;          // exclusive
    if (threadIdx.x == 255) bsum[blockIdx.x] = incl;
}

__global__ void scan_bsum_kernel(int* __restrict__ bsum, int nb) {
    __shared__ int tmp[1024];
    int t = threadIdx.x;
    int v = (t < nb) ? bsum[t] : 0;
    tmp[t] = v;
    __syncthreads();
    for (int off = 1; off < 1024; off <<= 1) {
        int x = (t >= off) ? tmp[t - off] : 0;
        __syncthreads();
        tmp[t] += x;
        __syncthreads();
    }
    if (t < nb) bsum[t] = tmp[t] - v;              // exclusive block offsets
}

__global__ void scan_add_kernel(int* __restrict__ starts,
                                const int* __restrict__ bsum,
                                int* __restrict__ cursor) {
    int g = blockIdx.x * 256 + threadIdx.x;
    if (g < SCAN_N) {
        int s = starts[g] + bsum[blockIdx.x];
        starts[g] = s;
        cursor[g] = s;
    }
}

// R2 structure (1 entry/thread, 3 chains) but a SINGLE packed 4B store per
// entry (half R2's store count), and nt input reads so the streaming inputs
// don't evict partially-filled destination lines from L2.
__global__ void scatter_kernel(const int* __restrict__ fr, const int* __restrict__ fc,
                               const float* __restrict__ fv,
                               const int* __restrict__ a1r, const int* __restrict__ a1c,
                               const float* __restrict__ a1v,
                               const int* __restrict__ a2r, const int* __restrict__ a2c,
                               const float* __restrict__ a2v,
                               int* __restrict__ cursor,
                               unsigned* __restrict__ spack) {
    int e = blockIdx.x * blockDim.x + threadIdx.x;
    if (e >= NNZ) return;
    int p;
    p = atomicAdd(&cursor[__builtin_nontemporal_load(&fr[e])], 1);
    spack[p] = pack_cv(__builtin_nontemporal_load(&fc[e]),
                       __builtin_nontemporal_load(&fv[e]));
    p = atomicAdd(&cursor[N_NODES + __builtin_nontemporal_load(&a1r[e])], 1);
    spack[p] = pack_cv(__builtin_nontemporal_load(&a1c[e]),
                       __builtin_nontemporal_load(&a1v[e]));
    p = atomicAdd(&cursor[2 * N_NODES + __builtin_nontemporal_load(&a2r[e])], 1);
    spack[p] = pack_cv(__builtin_nontemporal_load(&a2c[e]),
                       __builtin_nontemporal_load(&a2v[e]));
}

// -----------------------------------------------------------------------------
// Phase 1: per-row gather  xw{1,2}[r,:] = sum_e v_e * W{1,2}[c_e,:]
// 32-lane row group: ONE coalesced load of up to 32 packed records, then
// shfl-broadcast; j-loop unrolled x4 so 8 independent W loads are in flight.
// xw output is fp16 (halves phase-2 gather bytes; |xw|<8 so fp16 is safe).
// -----------------------------------------------------------------------------
__global__ void feat_gather_kernel(const int* __restrict__ starts,
                                   const unsigned* __restrict__ spack,
                                   const float4* __restrict__ W1,
                                   const float4* __restrict__ W2,
                                   ushort4* __restrict__ xw1h,
                                   ushort4* __restrict__ xw2h) {
    int lane = threadIdx.x & 31;
    int sub  = threadIdx.x >> 5;
    int r = blockIdx.x * 8 + sub;
    if (r >= N_NODES) return;
    int s = starts[r];
    int e = starts[r + 1];            // starts[50000] == 800000 (adj1 base)
    float4 a1 = make_float4(0.f, 0.f, 0.f, 0.f);
    float4 a2 = make_float4(0.f, 0.f, 0.f, 0.f);
    for (int base = s; base < e; base += 32) {
        int n = e - base;
        int m = (n < 32) ? n : 32;
        unsigned pk = (lane < m) ? spack[base + lane] : 0u;
        int j = 0;
        for (; j + 3 < m; j += 4) {
            unsigned p0 = __shfl(pk, j,     32);
            unsigned p1 = __shfl(pk, j + 1, 32);
            unsigned p2 = __shfl(pk, j + 2, 32);
            unsigned p3 = __shfl(pk, j + 3, 32);
            int c0 = upk_c(p0), c1 = upk_c(p1), c2 = upk_c(p2), c3 = upk_c(p3);
            float v0 = upk_v(p0), v1 = upk_v(p1), v2 = upk_v(p2), v3 = upk_v(p3);
            float4 w10 = W1[c0 * 32 + lane], w20 = W2[c0 * 32 + lane];
            float4 w11 = W1[c1 * 32 + lane], w21 = W2[c1 * 32 + lane];
            float4 w12 = W1[c2 * 32 + lane], w22 = W2[c2 * 32 + lane];
            float4 w13 = W1[c3 * 32 + lane], w23 = W2[c3 * 32 + lane];
            a1.x += v0 * w10.x; a1.y += v0 * w10.y; a1.z += v0 * w10.z; a1.w += v0 * w10.w;
            a2.x += v0 * w20.x; a2.y += v0 * w20.y; a2.z += v0 * w20.z; a2.w += v0 * w20.w;
            a1.x += v1 * w11.x; a1.y += v1 * w11.y; a1.z += v1 * w11.z; a1.w += v1 * w11.w;
            a2.x += v1 * w21.x; a2.y += v1 * w21.y; a2.z += v1 * w21.z; a2.w += v1 * w21.w;
            a1.x += v2 * w12.x; a1.y += v2 * w12.y; a1.z += v2 * w12.z; a1.w += v2 * w12.w;
            a2.x += v2 * w22.x; a2.y += v2 * w22.y; a2.z += v2 * w22.z; a2.w += v2 * w22.w;
            a1.x += v3 * w13.x; a1.y += v3 * w13.y; a1.z += v3 * w13.z; a1.w += v3 * w13.w;
            a2.x += v3 * w23.x; a2.y += v3 * w23.y; a2.z += v3 * w23.z; a2.w += v3 * w23.w;
        }
        for (; j < m; ++j) {
            unsigned pj = __shfl(pk, j, 32);
            int c = upk_c(pj);
            float v = upk_v(pj);
            float4 w1 = W1[c * 32 + lane];
            float4 w2 = W2[c * 32 + lane];
            a1.x += v * w1.x; a1.y += v * w1.y; a1.z += v * w1.z; a1.w += v * w1.w;
            a2.x += v * w2.x; a2.y += v * w2.y; a2.z += v * w2.z; a2.w += v * w2.w;
        }
    }
    ushort4 q1, q2;
    q1.x = __half_as_ushort(__float2half(a1.x)); q1.y = __half_as_ushort(__float2half(a1.y));
    q1.z = __half_as_ushort(__float2half(a1.z)); q1.w = __half_as_ushort(__float2half(a1.w));
    q2.x = __half_as_ushort(__float2half(a2.x)); q2.y = __half_as_ushort(__float2half(a2.y));
    q2.z = __half_as_ushort(__float2half(a2.z)); q2.w = __half_as_ushort(__float2half(a2.w));
    xw1h[r * 32 + lane] = q1;
    xw2h[r * 32 + lane] = q2;
}

// -----------------------------------------------------------------------------
// Phase 2: out[r,:] = relu( sum_adj1 v*xw1[c,:] + sum_adj2 v*xw2[c,:] )
// Same shfl-broadcast + x4 unroll; xw gathers are fp16 (8B/lane); out fp32
// written with nt stores (single-touch, keep xw resident in L2).
// -----------------------------------------------------------------------------
__global__ void adj_gather_kernel(const int* __restrict__ starts,
                                  const unsigned* __restrict__ spack,
                                  const ushort4* __restrict__ xw1h,
                                  const ushort4* __restrict__ xw2h,
                                  vf4* __restrict__ out) {
    int lane = threadIdx.x & 31;
    int sub  = threadIdx.x >> 5;
    int r = blockIdx.x * 8 + sub;
    if (r >= N_NODES) return;
    float4 acc = make_float4(0.f, 0.f, 0.f, 0.f);

    for (int rel = 0; rel < 2; ++rel) {
        int s = starts[(1 + rel) * N_NODES + r];
        int e = (rel == 1 && r == N_NODES - 1) ? TOTAL_NNZ
                                               : starts[(1 + rel) * N_NODES + r + 1];
        const ushort4* __restrict__ xw = (rel == 0) ? xw1h : xw2h;
        for (int base = s; base < e; base += 32) {
            int n = e - base;
            int m = (n < 32) ? n : 32;
            unsigned pk = (lane < m) ? spack[base + lane] : 0u;
            int j = 0;
            for (; j + 3 < m; j += 4) {
                unsigned p0 = __shfl(pk, j,     32);
                unsigned p1 = __shfl(pk, j + 1, 32);
                unsigned p2 = __shfl(pk, j + 2, 32);
                unsigned p3 = __shfl(pk, j + 3, 32);
                int c0 = upk_c(p0), c1 = upk_c(p1), c2 = upk_c(p2), c3 = upk_c(p3);
                float v0 = upk_v(p0), v1 = upk_v(p1), v2 = upk_v(p2), v3 = upk_v(p3);
                ushort4 x0 = xw[c0 * 32 + lane];
                ushort4 x1 = xw[c1 * 32 + lane];
                ushort4 x2 = xw[c2 * 32 + lane];
                ushort4 x3 = xw[c3 * 32 + lane];
                acc.x += v0 * h2f(x0.x); acc.y += v0 * h2f(x0.y);
                acc.z += v0 * h2f(x0.z); acc.w += v0 * h2f(x0.w);
                acc.x += v1 * h2f(x1.x); acc.y += v1 * h2f(x1.y);
                acc.z += v1 * h2f(x1.z); acc.w += v1 * h2f(x1.w);
                acc.x += v2 * h2f(x2.x); acc.y += v2 * h2f(x2.y);
                acc.z += v2 * h2f(x2.z); acc.w += v2 * h2f(x2.w);
                acc.x += v3 * h2f(x3.x); acc.y += v3 * h2f(x3.y);
                acc.z += v3 * h2f(x3.z); acc.w += v3 * h2f(x3.w);
            }
            for (; j < m; ++j) {
                unsigned pj = __shfl(pk, j, 32);
                int c = upk_c(pj);
                float v = upk_v(pj);
                ushort4 x = xw[c * 32 + lane];
                acc.x += v * h2f(x.x); acc.y += v * h2f(x.y);
                acc.z += v * h2f(x.z); acc.w += v * h2f(x.w);
            }
        }
    }
    vf4 res;
    res.x = fmaxf(acc.x, 0.f); res.y = fmaxf(acc.y, 0.f);
    res.z = fmaxf(acc.z, 0.f); res.w = fmaxf(acc.w, 0.f);
    __builtin_nontemporal_store(res, &out[r * 32 + lane]);
}

extern "C" void kernel_launch(void* const* d_in, const int* in_sizes, int n_in,
                              void* d_out, int out_size, void* d_ws, size_t ws_size,
                              hipStream_t stream) {
    const int*   feat_row  = (const int*)  d_in[0];
    const int*   feat_col  = (const int*)  d_in[1];
    const float* feat_vals = (const float*)d_in[2];
    const int*   adj1_row  = (const int*)  d_in[3];
    const int*   adj1_col  = (const int*)  d_in[4];
    const float* adj1_vals = (const float*)d_in[5];
    const int*   adj2_row  = (const int*)  d_in[6];
    const int*   adj2_col  = (const int*)  d_in[7];
    const float* adj2_vals = (const float*)d_in[8];
    const float* W1        = (const float*)d_in[9];
    const float* W2        = (const float*)d_in[10];

    // Workspace layout (all 16B-aligned offsets)
    char* ws = (char*)d_ws;
    ushort4*  xw1h  = (ushort4*)ws;             ws += (size_t)N_NODES * OUT_DIM * 2;  // 12.8 MB
    ushort4*  xw2h  = (ushort4*)ws;             ws += (size_t)N_NODES * OUT_DIM * 2;  // 12.8 MB
    unsigned* spack = (unsigned*)ws;            ws += (size_t)TOTAL_NNZ * 4;          // 9.6 MB
    int*      cnt   = (int*)ws;                 ws += (size_t)SCAN_N * 4;             // 600 KB
    int*      starts= (int*)ws;                 ws += (size_t)SCAN_N * 4;             // 600 KB
    int*      cursor= (int*)ws;                 ws += (size_t)SCAN_N * 4;             // 600 KB
    int*      bsum  = (int*)ws;                 ws += 1024 * 4;

    // Zero only the histogram counters (everything else is fully overwritten).
    (void)hipMemsetAsync(cnt, 0, SCAN_N * sizeof(int), stream);

    const int block = 256;

    const int grid_h = (NNZ / 4 + block - 1) / block;            // 782
    hist_kernel<<<grid_h, block, 0, stream>>>(
        (const vi4*)feat_row, (const vi4*)adj1_row, (const vi4*)adj2_row, cnt);

    scan_block_kernel<<<SCAN_BLOCKS, 256, 0, stream>>>(cnt, starts, bsum);
    scan_bsum_kernel<<<1, 1024, 0, stream>>>(bsum, SCAN_BLOCKS);
    scan_add_kernel<<<SCAN_BLOCKS, 256, 0, stream>>>(starts, bsum, cursor);

    const int grid_e = (NNZ + block - 1) / block;                // 3125
    scatter_kernel<<<grid_e, block, 0, stream>>>(
        feat_row, feat_col, feat_vals,
        adj1_row, adj1_col, adj1_vals,
        adj2_row, adj2_col, adj2_vals,
        cursor, spack);

    const int grid_rows = N_NODES / 8;                           // 6250 blocks, 8 rows each
    feat_gather_kernel<<<grid_rows, 256, 0, stream>>>(
        starts, spack, (const float4*)W1, (const float4*)W2, xw1h, xw2h);
    adj_gather_kernel<<<grid_rows, 256, 0, stream>>>(
        starts, spack, xw1h, xw2h, (vf4*)d_out);
}

// Round 8
// 385.505 us; speedup vs baseline: 1.5776x; 1.0595x over previous
//
#include <hip/hip_runtime.h>
#include <hip/hip_fp16.h>

// Problem constants (fixed by the reference setup)
#define N_NODES 50000
#define IN_DIM 256
#define OUT_DIM 128
#define NNZ 800000          // nnz for feat, adj1, adj2 each
#define SCAN_N (3 * N_NODES)        // 150000 row counters (feat | adj1 | adj2)
#define TOTAL_NNZ (3 * NNZ)         // 2.4M sorted entries
#define SCAN_BLOCKS ((SCAN_N + 255) / 256)   // 586
#define NPART 8                      // one row-partition per XCD
#define PART_W (N_NODES / NPART)     // 6250 rows per partition

// Native clang vector types — __builtin_nontemporal_* requires these.
typedef float vf4 __attribute__((ext_vector_type(4)));

// Packed entry: [col:16 | fp16(val):16].  adj cols < 50000 < 65536, feat cols < 256.
static __device__ __forceinline__ unsigned pack_cv(int c, float v) {
    return ((unsigned)c << 16) | (unsigned)__half_as_ushort(__float2half(v));
}
static __device__ __forceinline__ int   upk_c(unsigned pk) { return (int)(pk >> 16); }
static __device__ __forceinline__ float upk_v(unsigned pk) {
    return __half2float(__ushort_as_half((unsigned short)(pk & 0xffffu)));
}
static __device__ __forceinline__ float h2f(unsigned short h) {
    return __half2float(__ushort_as_half(h));
}

// -----------------------------------------------------------------------------
// CSR build: histogram -> exclusive scan -> scatter (counting sort by row).
// Unified segments: feat rows [0,50K), adj1 [50K,100K), adj2 [100K,150K).
//
// XCD partitioning: rows are split into 8 contiguous ranges (part = r/6250).
// blockIdx&7 round-robins across XCDs (HW dispatch heuristic), so all atomics
// and stores for a given row come from ONE XCD -> its L2 merges the ~16
// same-line stores into one writeback instead of 16 line bounces.
// -----------------------------------------------------------------------------
__global__ void hist_kernel(const int* __restrict__ fr,
                            const int* __restrict__ a1r,
                            const int* __restrict__ a2r,
                            int* __restrict__ cnt) {
    int part = blockIdx.x & (NPART - 1);
    int e = (blockIdx.x >> 3) * blockDim.x + threadIdx.x;
    if (e >= NNZ) return;
    int a = __builtin_nontemporal_load(&fr[e]);
    if (a / PART_W == part) atomicAdd(&cnt[a], 1);
    int b = __builtin_nontemporal_load(&a1r[e]);
    if (b / PART_W == part) atomicAdd(&cnt[N_NODES + b], 1);
    int c = __builtin_nontemporal_load(&a2r[e]);
    if (c / PART_W == part) atomicAdd(&cnt[2 * N_NODES + c], 1);
}

__global__ void scan_block_kernel(const int* __restrict__ cnt,
                                  int* __restrict__ starts,
                                  int* __restrict__ bsum) {
    __shared__ int tmp[256];
    int g = blockIdx.x * 256 + threadIdx.x;
    int v = (g < SCAN_N) ? cnt[g] : 0;
    tmp[threadIdx.x] = v;
    __syncthreads();
    for (int off = 1; off < 256; off <<= 1) {
        int t = (threadIdx.x >= off) ? tmp[threadIdx.x - off] : 0;
        __syncthreads();
        tmp[threadIdx.x] += t;
        __syncthreads();
    }
    int incl = tmp[threadIdx.x];
    if (g < SCAN_N) starts[g] = incl - v;          // exclusive
    if (threadIdx.x == 255) bsum[blockIdx.x] = incl;
}

__global__ void scan_bsum_kernel(int* __restrict__ bsum, int nb) {
    __shared__ int tmp[1024];
    int t = threadIdx.x;
    int v = (t < nb) ? bsum[t] : 0;
    tmp[t] = v;
    __syncthreads();
    for (int off = 1; off < 1024; off <<= 1) {
        int x = (t >= off) ? tmp[t - off] : 0;
        __syncthreads();
        tmp[t] += x;
        __syncthreads();
    }
    if (t < nb) bsum[t] = tmp[t] - v;              // exclusive block offsets
}

__global__ void scan_add_kernel(int* __restrict__ starts,
                                const int* __restrict__ bsum,
                                int* __restrict__ cursor) {
    int g = blockIdx.x * 256 + threadIdx.x;
    if (g < SCAN_N) {
        int s = starts[g] + bsum[blockIdx.x];
        starts[g] = s;
        cursor[g] = s;
    }
}

// XCD-partitioned scatter: each partition's blocks scan all edges but only
// scatter rows in their range. Streams are re-read 8x (L3-absorbed); in
// exchange the destination/cursor lines stay XCD-local and merge in L2.
__global__ void scatter_kernel(const int* __restrict__ fr, const int* __restrict__ fc,
                               const float* __restrict__ fv,
                               const int* __restrict__ a1r, const int* __restrict__ a1c,
                               const float* __restrict__ a1v,
                               const int* __restrict__ a2r, const int* __restrict__ a2c,
                               const float* __restrict__ a2v,
                               int* __restrict__ cursor,
                               unsigned* __restrict__ spack) {
    int part = blockIdx.x & (NPART - 1);
    int e = (blockIdx.x >> 3) * blockDim.x + threadIdx.x;
    if (e >= NNZ) return;
    int r = __builtin_nontemporal_load(&fr[e]);
    if (r / PART_W == part) {
        int p = atomicAdd(&cursor[r], 1);
        spack[p] = pack_cv(__builtin_nontemporal_load(&fc[e]),
                           __builtin_nontemporal_load(&fv[e]));
    }
    int r1 = __builtin_nontemporal_load(&a1r[e]);
    if (r1 / PART_W == part) {
        int p = atomicAdd(&cursor[N_NODES + r1], 1);
        spack[p] = pack_cv(__builtin_nontemporal_load(&a1c[e]),
                           __builtin_nontemporal_load(&a1v[e]));
    }
    int r2 = __builtin_nontemporal_load(&a2r[e]);
    if (r2 / PART_W == part) {
        int p = atomicAdd(&cursor[2 * N_NODES + r2], 1);
        spack[p] = pack_cv(__builtin_nontemporal_load(&a2c[e]),
                           __builtin_nontemporal_load(&a2v[e]));
    }
}

// -----------------------------------------------------------------------------
// Phase 1: per-row gather  xw{1,2}[r,:] = sum_e v_e * W{1,2}[c_e,:]
// 32-lane row group: ONE coalesced load of up to 32 packed records, then
// shfl-broadcast; j-loop unrolled x4 so 8 independent W loads are in flight.
// xw output is fp16 (halves phase-2 gather bytes; |xw|<8 so fp16 is safe).
// -----------------------------------------------------------------------------
__global__ void feat_gather_kernel(const int* __restrict__ starts,
                                   const unsigned* __restrict__ spack,
                                   const float4* __restrict__ W1,
                                   const float4* __restrict__ W2,
                                   ushort4* __restrict__ xw1h,
                                   ushort4* __restrict__ xw2h) {
    int lane = threadIdx.x & 31;
    int sub  = threadIdx.x >> 5;
    int r = blockIdx.x * 8 + sub;
    if (r >= N_NODES) return;
    int s = starts[r];
    int e = starts[r + 1];            // starts[50000] == 800000 (adj1 base)
    float4 a1 = make_float4(0.f, 0.f, 0.f, 0.f);
    float4 a2 = make_float4(0.f, 0.f, 0.f, 0.f);
    for (int base = s; base < e; base += 32) {
        int n = e - base;
        int m = (n < 32) ? n : 32;
        unsigned pk = (lane < m) ? spack[base + lane] : 0u;
        int j = 0;
        for (; j + 3 < m; j += 4) {
            unsigned p0 = __shfl(pk, j,     32);
            unsigned p1 = __shfl(pk, j + 1, 32);
            unsigned p2 = __shfl(pk, j + 2, 32);
            unsigned p3 = __shfl(pk, j + 3, 32);
            int c0 = upk_c(p0), c1 = upk_c(p1), c2 = upk_c(p2), c3 = upk_c(p3);
            float v0 = upk_v(p0), v1 = upk_v(p1), v2 = upk_v(p2), v3 = upk_v(p3);
            float4 w10 = W1[c0 * 32 + lane], w20 = W2[c0 * 32 + lane];
            float4 w11 = W1[c1 * 32 + lane], w21 = W2[c1 * 32 + lane];
            float4 w12 = W1[c2 * 32 + lane], w22 = W2[c2 * 32 + lane];
            float4 w13 = W1[c3 * 32 + lane], w23 = W2[c3 * 32 + lane];
            a1.x += v0 * w10.x; a1.y += v0 * w10.y; a1.z += v0 * w10.z; a1.w += v0 * w10.w;
            a2.x += v0 * w20.x; a2.y += v0 * w20.y; a2.z += v0 * w20.z; a2.w += v0 * w20.w;
            a1.x += v1 * w11.x; a1.y += v1 * w11.y; a1.z += v1 * w11.z; a1.w += v1 * w11.w;
            a2.x += v1 * w21.x; a2.y += v1 * w21.y; a2.z += v1 * w21.z; a2.w += v1 * w21.w;
            a1.x += v2 * w12.x; a1.y += v2 * w12.y; a1.z += v2 * w12.z; a1.w += v2 * w12.w;
            a2.x += v2 * w22.x; a2.y += v2 * w22.y; a2.z += v2 * w22.z; a2.w += v2 * w22.w;
            a1.x += v3 * w13.x; a1.y += v3 * w13.y; a1.z += v3 * w13.z; a1.w += v3 * w13.w;
            a2.x += v3 * w23.x; a2.y += v3 * w23.y; a2.z += v3 * w23.z; a2.w += v3 * w23.w;
        }
        for (; j < m; ++j) {
            unsigned pj = __shfl(pk, j, 32);
            int c = upk_c(pj);
            float v = upk_v(pj);
            float4 w1 = W1[c * 32 + lane];
            float4 w2 = W2[c * 32 + lane];
            a1.x += v * w1.x; a1.y += v * w1.y; a1.z += v * w1.z; a1.w += v * w1.w;
            a2.x += v * w2.x; a2.y += v * w2.y; a2.z += v * w2.z; a2.w += v * w2.w;
        }
    }
    ushort4 q1, q2;
    q1.x = __half_as_ushort(__float2half(a1.x)); q1.y = __half_as_ushort(__float2half(a1.y));
    q1.z = __half_as_ushort(__float2half(a1.z)); q1.w = __half_as_ushort(__float2half(a1.w));
    q2.x = __half_as_ushort(__float2half(a2.x)); q2.y = __half_as_ushort(__float2half(a2.y));
    q2.z = __half_as_ushort(__float2half(a2.z)); q2.w = __half_as_ushort(__float2half(a2.w));
    xw1h[r * 32 + lane] = q1;
    xw2h[r * 32 + lane] = q2;
}

// -----------------------------------------------------------------------------
// Phase 2: out[r,:] = relu( sum_adj1 v*xw1[c,:] + sum_adj2 v*xw2[c,:] )
// Same shfl-broadcast + x4 unroll; xw gathers are fp16 (8B/lane); out fp32
// written with nt stores (single-touch, keep xw resident in L2).
// -----------------------------------------------------------------------------
__global__ void adj_gather_kernel(const int* __restrict__ starts,
                                  const unsigned* __restrict__ spack,
                                  const ushort4* __restrict__ xw1h,
                                  const ushort4* __restrict__ xw2h,
                                  vf4* __restrict__ out) {
    int lane = threadIdx.x & 31;
    int sub  = threadIdx.x >> 5;
    int r = blockIdx.x * 8 + sub;
    if (r >= N_NODES) return;
    float4 acc = make_float4(0.f, 0.f, 0.f, 0.f);

    for (int rel = 0; rel < 2; ++rel) {
        int s = starts[(1 + rel) * N_NODES + r];
        int e = (rel == 1 && r == N_NODES - 1) ? TOTAL_NNZ
                                               : starts[(1 + rel) * N_NODES + r + 1];
        const ushort4* __restrict__ xw = (rel == 0) ? xw1h : xw2h;
        for (int base = s; base < e; base += 32) {
            int n = e - base;
            int m = (n < 32) ? n : 32;
            unsigned pk = (lane < m) ? spack[base + lane] : 0u;
            int j = 0;
            for (; j + 3 < m; j += 4) {
                unsigned p0 = __shfl(pk, j,     32);
                unsigned p1 = __shfl(pk, j + 1, 32);
                unsigned p2 = __shfl(pk, j + 2, 32);
                unsigned p3 = __shfl(pk, j + 3, 32);
                int c0 = upk_c(p0), c1 = upk_c(p1), c2 = upk_c(p2), c3 = upk_c(p3);
                float v0 = upk_v(p0), v1 = upk_v(p1), v2 = upk_v(p2), v3 = upk_v(p3);
                ushort4 x0 = xw[c0 * 32 + lane];
                ushort4 x1 = xw[c1 * 32 + lane];
                ushort4 x2 = xw[c2 * 32 + lane];
                ushort4 x3 = xw[c3 * 32 + lane];
                acc.x += v0 * h2f(x0.x); acc.y += v0 * h2f(x0.y);
                acc.z += v0 * h2f(x0.z); acc.w += v0 * h2f(x0.w);
                acc.x += v1 * h2f(x1.x); acc.y += v1 * h2f(x1.y);
                acc.z += v1 * h2f(x1.z); acc.w += v1 * h2f(x1.w);
                acc.x += v2 * h2f(x2.x); acc.y += v2 * h2f(x2.y);
                acc.z += v2 * h2f(x2.z); acc.w += v2 * h2f(x2.w);
                acc.x += v3 * h2f(x3.x); acc.y += v3 * h2f(x3.y);
                acc.z += v3 * h2f(x3.z); acc.w += v3 * h2f(x3.w);
            }
            for (; j < m; ++j) {
                unsigned pj = __shfl(pk, j, 32);
                int c = upk_c(pj);
                float v = upk_v(pj);
                ushort4 x = xw[c * 32 + lane];
                acc.x += v * h2f(x.x); acc.y += v * h2f(x.y);
                acc.z += v * h2f(x.z); acc.w += v * h2f(x.w);
            }
        }
    }
    vf4 res;
    res.x = fmaxf(acc.x, 0.f); res.y = fmaxf(acc.y, 0.f);
    res.z = fmaxf(acc.z, 0.f); res.w = fmaxf(acc.w, 0.f);
    __builtin_nontemporal_store(res, &out[r * 32 + lane]);
}

extern "C" void kernel_launch(void* const* d_in, const int* in_sizes, int n_in,
                              void* d_out, int out_size, void* d_ws, size_t ws_size,
                              hipStream_t stream) {
    const int*   feat_row  = (const int*)  d_in[0];
    const int*   feat_col  = (const int*)  d_in[1];
    const float* feat_vals = (const float*)d_in[2];
    const int*   adj1_row  = (const int*)  d_in[3];
    const int*   adj1_col  = (const int*)  d_in[4];
    const float* adj1_vals = (const float*)d_in[5];
    const int*   adj2_row  = (const int*)  d_in[6];
    const int*   adj2_col  = (const int*)  d_in[7];
    const float* adj2_vals = (const float*)d_in[8];
    const float* W1        = (const float*)d_in[9];
    const float* W2        = (const float*)d_in[10];

    // Workspace layout (all 16B-aligned offsets)
    char* ws = (char*)d_ws;
    ushort4*  xw1h  = (ushort4*)ws;             ws += (size_t)N_NODES * OUT_DIM * 2;  // 12.8 MB
    ushort4*  xw2h  = (ushort4*)ws;             ws += (size_t)N_NODES * OUT_DIM * 2;  // 12.8 MB
    unsigned* spack = (unsigned*)ws;            ws += (size_t)TOTAL_NNZ * 4;          // 9.6 MB
    int*      cnt   = (int*)ws;                 ws += (size_t)SCAN_N * 4;             // 600 KB
    int*      starts= (int*)ws;                 ws += (size_t)SCAN_N * 4;             // 600 KB
    int*      cursor= (int*)ws;                 ws += (size_t)SCAN_N * 4;             // 600 KB
    int*      bsum  = (int*)ws;                 ws += 1024 * 4;

    // Zero only the histogram counters (everything else is fully overwritten).
    (void)hipMemsetAsync(cnt, 0, SCAN_N * sizeof(int), stream);

    const int block = 256;

    // 8 partitions x 3125 chunks; blockIdx&7 = partition = XCD (round-robin).
    const int grid_part = NPART * ((NNZ + block - 1) / block);   // 25000
    hist_kernel<<<grid_part, block, 0, stream>>>(
        feat_row, adj1_row, adj2_row, cnt);

    scan_block_kernel<<<SCAN_BLOCKS, 256, 0, stream>>>(cnt, starts, bsum);
    scan_bsum_kernel<<<1, 1024, 0, stream>>>(bsum, SCAN_BLOCKS);
    scan_add_kernel<<<SCAN_BLOCKS, 256, 0, stream>>>(starts, bsum, cursor);

    scatter_kernel<<<grid_part, block, 0, stream>>>(
        feat_row, feat_col, feat_vals,
        adj1_row, adj1_col, adj1_vals,
        adj2_row, adj2_col, adj2_vals,
        cursor, spack);

    const int grid_rows = N_NODES / 8;                           // 6250 blocks, 8 rows each
    feat_gather_kernel<<<grid_rows, 256, 0, stream>>>(
        starts, spack, (const float4*)W1, (const float4*)W2, xw1h, xw2h);
    adj_gather_kernel<<<grid_rows, 256, 0, stream>>>(
        starts, spack, xw1h, xw2h, (vf4*)d_out);
}